// Round 13
// baseline (87.398 us; speedup 1.0000x reference)
//
#include <hip/hip_runtime.h>

// Dims
#define SS 96       // spatial
#define CC 32       // latent
#define TT 16       // time
#define BP 16       // B*P
#define MM 3072     // CC*SS; m = c*96 + e == x's natural [c][e] flat layout
#define KTOT 49152  // TT*MM: flattened (t,m) contraction axis for GEMM2
#define NKB 48      // split-K partial count in GEMM2

typedef float f32x4 __attribute__((ext_vector_type(4)));
typedef short short8 __attribute__((ext_vector_type(8)));

// fp32 -> bf16 round-to-nearest-even
__device__ __forceinline__ unsigned short f2b(float f) {
    union { float f; unsigned u; } a; a.f = f;
    unsigned r = a.u + 0x7FFFu + ((a.u >> 16) & 1u);
    return (unsigned short)(r >> 16);
}

// ---------------------------------------------------------------------------
// K1: prep (grid 288):
//   [0,96):    Kt[X][c*96+e] = K[X][e*32+c]                  (fp32)
//   [96,192):  Qb[(c*96+e)][v] = bf16(Q[v][e*32+c])          (A of GEMM1)
//   [192,288): wab[X][t*96+v] = bf16(w[v]*Aoo[X][v*16+t])    (B of GEMM1)
//   block 0 additionally zeroes the takeover counter (replay-safe).
__global__ __launch_bounds__(256) void k_prep(
    const float* __restrict__ Q, const float* __restrict__ K,
    const float* __restrict__ Aoo, const float* __restrict__ w,
    float* __restrict__ Kt, unsigned short* __restrict__ Qb,
    unsigned short* __restrict__ wab, unsigned int* __restrict__ cnt)
{
    __shared__ float sb[SS * 33];
    const int bid = blockIdx.x, tid = threadIdx.x;
    if (bid == 0 && tid == 0) *cnt = 0u;
    if (bid < 96) {
        const int X = bid;
        const float* src = K + (size_t)X * MM;
        float* dst = Kt + (size_t)X * MM;
        for (int i = tid; i < MM; i += 256) {
            int e = i >> 5, c = i & 31;
            sb[e * 33 + c] = src[i];
        }
        __syncthreads();
        for (int j = tid; j < MM; j += 256) {
            int c = j / SS, e = j - c * SS;
            dst[j] = sb[e * 33 + c];
        }
    } else if (bid < 192) {
        const int e = bid - 96;                    // one e-slab: all (v, c)
        for (int i = tid; i < MM; i += 256) {      // i = v*32 + c
            int v = i >> 5, c = i & 31;
            sb[v * 33 + c] = Q[(size_t)v * MM + e * 32 + c];
        }
        __syncthreads();
        for (int j = tid; j < MM; j += 256) {      // j = c*96 + v
            int c = j / SS, v = j - c * SS;
            Qb[(size_t)(c * SS + e) * SS + v] = f2b(sb[v * 33 + c]);
        }
    } else {
        const int X = bid - 192;
        for (int i = tid; i < SS * TT; i += 256) { // i = v*16 + t
            int v = i >> 4, t = i & 15;
            sb[v * 17 + t] = Aoo[(size_t)X * (SS * TT) + i];
        }
        __syncthreads();
        for (int j = tid; j < SS * TT; j += 256) { // j = t*96 + v
            int t = j / SS, v = j - t * SS;
            wab[(size_t)X * (SS * TT) + j] = f2b(w[v] * sb[v * 17 + t]);
        }
    }
}

// ---------------------------------------------------------------------------
// K2 (GEMM1 + xb convert + q GEMV, grid 1728):
//   [0,1152):    per (X, mc): C[m(256) x t(16)] = Qb[m,v] x wab[t,v]^T, then
//                W2[X][t*3072+m] = bf16(C * Kt[X][m]).
//   [1152,1536): xb = bf16(x) (natural flat layout) — feeds GEMM2 only.
//   [1536,1728): q[bp][X][c] = sum_e V[X,e,c]*x[bp,T-1,c,e] — feeds finale only.
__global__ __launch_bounds__(256) void k_gemm1x(
    const unsigned short* __restrict__ Qb, const unsigned short* __restrict__ wab,
    const float* __restrict__ Kt, const float* __restrict__ x,
    const float* __restrict__ V, unsigned short* __restrict__ W2,
    unsigned short* __restrict__ xb, float* __restrict__ q)
{
    __shared__ float smem[SS * 33];     // used by the q path only
    const int tid = threadIdx.x, bid = blockIdx.x;
    if (bid >= 1536) {
        // ---- q path: one block per (bp, xc)
        const int qb = bid - 1536;
        const int bp = qb / 12, xc = qb - (qb / 12) * 12;
        const float* xs = x + (size_t)bp * (TT * MM) + (TT - 1) * MM;  // [c][e]
        for (int i = tid; i < MM; i += 256) {
            int c = i / SS, e = i - (i / SS) * SS;
            smem[e * 33 + c] = xs[i];
        }
        __syncthreads();
        const int c = tid & 31, grp = tid >> 5;
        const int X = xc * 8 + grp;
        const float* Vp = V + (size_t)X * MM + c;    // coalesced across c lanes
        float acc = 0.f;
#pragma unroll 8
        for (int e = 0; e < SS; ++e)
            acc = fmaf(Vp[e * CC], smem[e * 33 + c], acc);
        q[((size_t)bp * SS + X) * CC + c] = acc;     // coalesced store
        return;
    }
    if (bid >= 1152) {
        const size_t base = ((size_t)(bid - 1152) * 256 + tid) * 8;
        float4 a = *(const float4*)(x + base);
        float4 b = *(const float4*)(x + base + 4);
        ushort4 o0, o1;
        o0.x = f2b(a.x); o0.y = f2b(a.y); o0.z = f2b(a.z); o0.w = f2b(a.w);
        o1.x = f2b(b.x); o1.y = f2b(b.y); o1.z = f2b(b.z); o1.w = f2b(b.w);
        *(ushort4*)(xb + base) = o0;
        *(ushort4*)(xb + base + 4) = o1;
        return;
    }
    const int X = bid / 12;
    const int mc = bid - X * 12;
    const int lane = tid & 63, wv = tid >> 6;
    const int mbase = mc * 256 + wv * 64;
    const int l15 = lane & 15, lg = lane >> 4;

    const unsigned short* bw = wab + (size_t)X * (SS * TT) + l15 * SS + lg * 8;
    const short8 bf0 = *(const short8*)(bw);
    const short8 bf1 = *(const short8*)(bw + 32);
    const short8 bf2 = *(const short8*)(bw + 64);

    const f32x4 zero = {0.f, 0.f, 0.f, 0.f};
#pragma unroll
    for (int nt = 0; nt < 4; ++nt) {
        const int mrow = mbase + nt * 16 + l15;
        const unsigned short* ap = Qb + (size_t)mrow * SS + lg * 8;
        const short8 a0 = *(const short8*)(ap);
        const short8 a1 = *(const short8*)(ap + 32);
        const short8 a2 = *(const short8*)(ap + 64);
        f32x4 acc = zero;
        acc = __builtin_amdgcn_mfma_f32_16x16x32_bf16(a0, bf0, acc, 0, 0, 0);
        acc = __builtin_amdgcn_mfma_f32_16x16x32_bf16(a1, bf1, acc, 0, 0, 0);
        acc = __builtin_amdgcn_mfma_f32_16x16x32_bf16(a2, bf2, acc, 0, 0, 0);
        const int mout = mbase + nt * 16 + lg * 4;     // 4 consecutive m (r)
        const f32x4 kt4 = *(const f32x4*)(Kt + (size_t)X * MM + mout);
        ushort4 o;
        o.x = f2b(acc[0] * kt4[0]);
        o.y = f2b(acc[1] * kt4[1]);
        o.z = f2b(acc[2] * kt4[2]);
        o.w = f2b(acc[3] * kt4[3]);
        *(ushort4*)(W2 + (size_t)X * KTOT + (size_t)l15 * MM + mout) = o;
    }
}

// ---------------------------------------------------------------------------
// K3 (GEMM2 split-K + takeover finale, grid 288):
//   each (kb, Xt) block: Gp[((Xt*16+Xl)*16+b)*48+kb] = partial dot, then
//   fence + device-scope counter. The 288th arrival sums Gp (fixed kb order,
//   deterministic) and computes y = q·G. No atomic accumulation anywhere.
__global__ __launch_bounds__(256) void k_gemm2f(
    const unsigned short* __restrict__ W2, const unsigned short* __restrict__ xb,
    const float* __restrict__ q, float* __restrict__ Gp,
    unsigned int* __restrict__ cnt, float* __restrict__ y)
{
    __shared__ float red[1024];
    __shared__ float Gl[SS * BP];
    __shared__ unsigned int winner_s;
    const int tid = threadIdx.x, bid = blockIdx.x;
    const int kb = bid / 6, Xt = bid - (bid / 6) * 6;
    const int lane = tid & 63, wv = tid >> 6;
    const int l15 = lane & 15, lg = lane >> 4;
    const int k0 = kb * 1024 + wv * 256;

    f32x4 acc = {0.f, 0.f, 0.f, 0.f};
    const unsigned short* xrow = xb + (size_t)l15 * KTOT + k0 + lg * 8;
    const unsigned short* arow =
        W2 + (size_t)(Xt * 16 + l15) * KTOT + k0 + lg * 8;
#pragma unroll
    for (int ks = 0; ks < 8; ++ks) {
        const short8 bf = *(const short8*)(xrow + ks * 32);
        const short8 af = *(const short8*)(arow + ks * 32);
        acc = __builtin_amdgcn_mfma_f32_16x16x32_bf16(af, bf, acc, 0, 0, 0);
    }
#pragma unroll
    for (int r = 0; r < 4; ++r)
        red[(wv * 64 + lane) * 4 + r] = acc[r];
    __syncthreads();
    {   // i = Xl*16 + b; C layout: col(l&15)=b, row((l>>4)*4+r)=Xl
        const int Xl = tid >> 4, b = tid & 15;
        const int l = (Xl >> 2) * 16 + b, r = Xl & 3;
        float s = red[(0 * 64 + l) * 4 + r] + red[(1 * 64 + l) * 4 + r] +
                  red[(2 * 64 + l) * 4 + r] + red[(3 * 64 + l) * 4 + r];
        Gp[(size_t)((Xt * 16 + Xl) * BP + b) * NKB + kb] = s;
    }

    // ---- takeover: last block to arrive runs the finale
    __threadfence();
    if (tid == 0)
        winner_s = __hip_atomic_fetch_add(cnt, 1u, __ATOMIC_ACQ_REL,
                                          __HIP_MEMORY_SCOPE_AGENT);
    __syncthreads();
    if (winner_s != 287u) return;
    __threadfence();

    // G[X*16+b] = sum_kb Gp (contiguous 48-float runs, fixed order)
    for (int i = tid; i < SS * BP; i += 256) {
        const float* p = Gp + (size_t)i * NKB;
        float s = 0.f;
#pragma unroll
        for (int j = 0; j < 12; ++j) {
            f32x4 v4 = *(const f32x4*)(p + j * 4);
            s += v4[0] + v4[1] + v4[2] + v4[3];
        }
        Gl[i] = s;
    }
    __syncthreads();

    // y[bp,c] = sum_X q[bp,X,c] * G[X,bp]; 512 outputs in 2 passes
#pragma unroll
    for (int pass = 0; pass < 2; ++pass) {
        const int bp = (tid >> 5) + pass * 8;
        const int c = tid & 31;
        const float* qp = q + (size_t)bp * (SS * CC) + c;
        float accy = 0.f;
#pragma unroll 8
        for (int X = 0; X < SS; ++X)
            accy = fmaf(qp[X * CC], Gl[X * BP + bp], accy);
        y[bp * CC + c] = accy;
    }
}

// ---------------------------------------------------------------------------
extern "C" void kernel_launch(void* const* d_in, const int* in_sizes, int n_in,
                              void* d_out, int out_size, void* d_ws, size_t ws_size,
                              hipStream_t stream) {
    const float* x   = (const float*)d_in[0];
    const float* Q   = (const float*)d_in[1];
    const float* K   = (const float*)d_in[2];
    const float* V   = (const float*)d_in[3];
    const float* Aoo = (const float*)d_in[4];
    const float* w   = (const float*)d_in[5];

    char* wsb = (char*)d_ws;                       // 16B-aligned offsets
    float*          Kt  = (float*)(wsb);                    // 1,179,648 B
    float*          Gp  = (float*)(wsb + 1179648);          //   294,912 B
    float*          qb_ = (float*)(wsb + 1474560);          //   196,608 B
    unsigned short* Qb  = (unsigned short*)(wsb + 1671168); //   589,824 B
    unsigned short* wab = (unsigned short*)(wsb + 2260992); //   294,912 B
    unsigned short* xb  = (unsigned short*)(wsb + 2555904); // 1,572,864 B
    unsigned short* W2  = (unsigned short*)(wsb + 4128768); // 9,437,184 B
    unsigned int*   cnt = (unsigned int*)(wsb + 13565952);  //        16 B
    float* y = (float*)d_out;                      // total ws: ~13.6 MB

    k_prep<<<dim3(288), 256, 0, stream>>>(Q, K, Aoo, w, Kt, Qb, wab, cnt);
    k_gemm1x<<<dim3(1728), 256, 0, stream>>>(Qb, wab, Kt, x, V, W2, xb, qb_);
    k_gemm2f<<<dim3(288), 256, 0, stream>>>(W2, xb, qb_, Gp, cnt, y);
}

// Round 14
// 38.741 us; speedup vs baseline: 2.2560x; 2.2560x over previous
//
#include <hip/hip_runtime.h>

// Dims
#define SS 96       // spatial
#define CC 32       // latent
#define TT 16       // time
#define BP 16       // B*P
#define MM 3072     // CC*SS; m = c*96 + e == x's natural [c][e] flat layout
#define KTOT 49152  // TT*MM: flattened (t,m) contraction axis for GEMM2

typedef float f32x4 __attribute__((ext_vector_type(4)));
typedef short short8 __attribute__((ext_vector_type(8)));

// fp32 -> bf16 round-to-nearest-even
__device__ __forceinline__ unsigned short f2b(float f) {
    union { float f; unsigned u; } a; a.f = f;
    unsigned r = a.u + 0x7FFFu + ((a.u >> 16) & 1u);
    return (unsigned short)(r >> 16);
}

// ---------------------------------------------------------------------------
// K1: prep (grid 288):
//   [0,96):    Kt[X][c*96+e] = K[X][e*32+c]                  (fp32)
//   [96,192):  Qb[(c*96+e)][v] = bf16(Q[v][e*32+c])          (A of GEMM1)
//   [192,288): wab[X][t*96+v] = bf16(w[v]*Aoo[X][v*16+t])    (B of GEMM1)
//   block 0 additionally zeroes y (atomic-accumulated later; replay-safe).
__global__ __launch_bounds__(256) void k_prep(
    const float* __restrict__ Q, const float* __restrict__ K,
    const float* __restrict__ Aoo, const float* __restrict__ w,
    float* __restrict__ Kt, unsigned short* __restrict__ Qb,
    unsigned short* __restrict__ wab, float* __restrict__ y)
{
    __shared__ float sb[SS * 33];
    const int bid = blockIdx.x, tid = threadIdx.x;
    if (bid == 0) { y[tid] = 0.f; y[tid + 256] = 0.f; }
    if (bid < 96) {
        const int X = bid;
        const float* src = K + (size_t)X * MM;
        float* dst = Kt + (size_t)X * MM;
        for (int i = tid; i < MM; i += 256) {
            int e = i >> 5, c = i & 31;
            sb[e * 33 + c] = src[i];
        }
        __syncthreads();
        for (int j = tid; j < MM; j += 256) {
            int c = j / SS, e = j - c * SS;
            dst[j] = sb[e * 33 + c];
        }
    } else if (bid < 192) {
        const int e = bid - 96;                    // one e-slab: all (v, c)
        for (int i = tid; i < MM; i += 256) {      // i = v*32 + c
            int v = i >> 5, c = i & 31;
            sb[v * 33 + c] = Q[(size_t)v * MM + e * 32 + c];
        }
        __syncthreads();
        for (int j = tid; j < MM; j += 256) {      // j = c*96 + v
            int c = j / SS, v = j - c * SS;
            Qb[(size_t)(c * SS + e) * SS + v] = f2b(sb[v * 33 + c]);
        }
    } else {
        const int X = bid - 192;
        for (int i = tid; i < SS * TT; i += 256) { // i = v*16 + t
            int v = i >> 4, t = i & 15;
            sb[v * 17 + t] = Aoo[(size_t)X * (SS * TT) + i];
        }
        __syncthreads();
        for (int j = tid; j < SS * TT; j += 256) { // j = t*96 + v
            int t = j / SS, v = j - t * SS;
            wab[(size_t)X * (SS * TT) + j] = f2b(w[v] * sb[v * 17 + t]);
        }
    }
}

// ---------------------------------------------------------------------------
// K2 (GEMM1 + xb convert + q GEMV, grid 1728):
//   [0,1152):    per (X, mc): C[m(256) x t(16)] = Qb[m,v] x wab[t,v]^T, then
//                W2[X][t*3072+m] = bf16(C * Kt[X][m]). Output restaged via
//                LDS so global stores are 512B contiguous rows (R12's were
//                8B/lane @ 6KB stride).
//   [1152,1536): xb = bf16(x) (natural flat layout) — feeds GEMM2 only.
//   [1536,1728): q[bp][X][c] = sum_e V[X,e,c]*x[bp,T-1,c,e] — feeds y only.
__global__ __launch_bounds__(256) void k_gemm1x(
    const unsigned short* __restrict__ Qb, const unsigned short* __restrict__ wab,
    const float* __restrict__ Kt, const float* __restrict__ x,
    const float* __restrict__ V, unsigned short* __restrict__ W2,
    unsigned short* __restrict__ xb, float* __restrict__ q)
{
    __shared__ float smem[SS * 33];
    const int tid = threadIdx.x, bid = blockIdx.x;
    if (bid >= 1536) {
        // ---- q path: one block per (bp, xc)
        const int qb = bid - 1536;
        const int bp = qb / 12, xc = qb - (qb / 12) * 12;
        const float* xs = x + (size_t)bp * (TT * MM) + (TT - 1) * MM;  // [c][e]
        for (int i = tid; i < MM; i += 256) {
            int c = i / SS, e = i - (i / SS) * SS;
            smem[e * 33 + c] = xs[i];
        }
        __syncthreads();
        const int c = tid & 31, grp = tid >> 5;
        const int X = xc * 8 + grp;
        const float* Vp = V + (size_t)X * MM + c;    // coalesced across c lanes
        float acc = 0.f;
#pragma unroll 8
        for (int e = 0; e < SS; ++e)
            acc = fmaf(Vp[e * CC], smem[e * 33 + c], acc);
        q[((size_t)bp * SS + X) * CC + c] = acc;     // coalesced store
        return;
    }
    if (bid >= 1152) {
        const size_t base = ((size_t)(bid - 1152) * 256 + tid) * 8;
        float4 a = *(const float4*)(x + base);
        float4 b = *(const float4*)(x + base + 4);
        ushort4 o0, o1;
        o0.x = f2b(a.x); o0.y = f2b(a.y); o0.z = f2b(a.z); o0.w = f2b(a.w);
        o1.x = f2b(b.x); o1.y = f2b(b.y); o1.z = f2b(b.z); o1.w = f2b(b.w);
        *(ushort4*)(xb + base) = o0;
        *(ushort4*)(xb + base + 4) = o1;
        return;
    }
    const int X = bid / 12;
    const int mc = bid - X * 12;
    const int lane = tid & 63, wv = tid >> 6;
    const int mbase = mc * 256 + wv * 64;
    const int l15 = lane & 15, lg = lane >> 4;
    unsigned short* w2s = (unsigned short*)smem;     // [16 t][256 m] bf16, 8KB

    const unsigned short* bw = wab + (size_t)X * (SS * TT) + l15 * SS + lg * 8;
    const short8 bf0 = *(const short8*)(bw);
    const short8 bf1 = *(const short8*)(bw + 32);
    const short8 bf2 = *(const short8*)(bw + 64);

    const f32x4 zero = {0.f, 0.f, 0.f, 0.f};
#pragma unroll
    for (int nt = 0; nt < 4; ++nt) {
        const int mrow = mbase + nt * 16 + l15;
        const unsigned short* ap = Qb + (size_t)mrow * SS + lg * 8;
        const short8 a0 = *(const short8*)(ap);
        const short8 a1 = *(const short8*)(ap + 32);
        const short8 a2 = *(const short8*)(ap + 64);
        f32x4 acc = zero;
        acc = __builtin_amdgcn_mfma_f32_16x16x32_bf16(a0, bf0, acc, 0, 0, 0);
        acc = __builtin_amdgcn_mfma_f32_16x16x32_bf16(a1, bf1, acc, 0, 0, 0);
        acc = __builtin_amdgcn_mfma_f32_16x16x32_bf16(a2, bf2, acc, 0, 0, 0);
        const int mloc = wv * 64 + nt * 16 + lg * 4;   // local m of 4 elems
        const f32x4 kt4 = *(const f32x4*)(Kt + (size_t)X * MM + mc * 256 + mloc);
        ushort4 o;
        o.x = f2b(acc[0] * kt4[0]);
        o.y = f2b(acc[1] * kt4[1]);
        o.z = f2b(acc[2] * kt4[2]);
        o.w = f2b(acc[3] * kt4[3]);
        *(ushort4*)(w2s + l15 * 256 + mloc) = o;       // C row t=l15
    }
    __syncthreads();
    // coalesced store: 16 rows x 512B; 512 ushort8-groups over 2 passes
#pragma unroll
    for (int i = tid; i < 512; i += 256) {
        const int t = i >> 5, col = (i & 31) * 8;
        *(short8*)(W2 + (size_t)X * KTOT + (size_t)t * MM + mc * 256 + col) =
            *(const short8*)(w2s + t * 256 + col);
    }
}

// ---------------------------------------------------------------------------
// K3 (GEMM2 split-K + fused y-partial, grid 288 = 48 kb x 6 Xt):
//   Gloc[Xl,b] = sum_{k in kb-chunk} W2[Xt*16+Xl, k] * xb[b, k]  (LDS only),
//   then y[bp,c] += sum_Xl q[bp, Xt*16+Xl, c] * Gloc[Xl, bp]  (atomicAdd).
// No fences, no Gp global traffic, no 4th kernel. fp32 atomic ordering
// jitter ~1e-6 << 4.5e-5 threshold (same pattern as R2/R3, passed).
__global__ __launch_bounds__(256) void k_gemm2y(
    const unsigned short* __restrict__ W2, const unsigned short* __restrict__ xb,
    const float* __restrict__ q, float* __restrict__ y)
{
    __shared__ float red[1024];
    __shared__ float Gloc[256];
    const int tid = threadIdx.x, bid = blockIdx.x;
    const int kb = bid / 6, Xt = bid - (bid / 6) * 6;
    const int lane = tid & 63, wv = tid >> 6;
    const int l15 = lane & 15, lg = lane >> 4;
    const int k0 = kb * 1024 + wv * 256;

    f32x4 acc = {0.f, 0.f, 0.f, 0.f};
    const unsigned short* xrow = xb + (size_t)l15 * KTOT + k0 + lg * 8;
    const unsigned short* arow =
        W2 + (size_t)(Xt * 16 + l15) * KTOT + k0 + lg * 8;
#pragma unroll
    for (int ks = 0; ks < 8; ++ks) {
        const short8 bf = *(const short8*)(xrow + ks * 32);
        const short8 af = *(const short8*)(arow + ks * 32);
        acc = __builtin_amdgcn_mfma_f32_16x16x32_bf16(af, bf, acc, 0, 0, 0);
    }
#pragma unroll
    for (int r = 0; r < 4; ++r)
        red[(wv * 64 + lane) * 4 + r] = acc[r];
    __syncthreads();
    {   // C layout: col(l&15)=b, row((l>>4)*4+r)=Xl  (verified R11/R12)
        const int Xl = tid >> 4, b = tid & 15;
        const int l = (Xl >> 2) * 16 + b, r = Xl & 3;
        Gloc[Xl * BP + b] = red[(0 * 64 + l) * 4 + r] + red[(1 * 64 + l) * 4 + r] +
                            red[(2 * 64 + l) * 4 + r] + red[(3 * 64 + l) * 4 + r];
    }
    __syncthreads();

    // y-partial: 512 outputs over 2 passes; q reads coalesced (c contiguous)
#pragma unroll
    for (int pass = 0; pass < 2; ++pass) {
        const int out = tid + pass * 256;
        const int bp = out >> 5, c = out & 31;
        const float* qp = q + ((size_t)bp * SS + Xt * 16) * CC + c;
        float a = 0.f;
#pragma unroll
        for (int Xl = 0; Xl < 16; ++Xl)
            a = fmaf(qp[(size_t)Xl * CC], Gloc[Xl * BP + bp], a);
        atomicAdd(&y[out], a);
    }
}

// ---------------------------------------------------------------------------
extern "C" void kernel_launch(void* const* d_in, const int* in_sizes, int n_in,
                              void* d_out, int out_size, void* d_ws, size_t ws_size,
                              hipStream_t stream) {
    const float* x   = (const float*)d_in[0];
    const float* Q   = (const float*)d_in[1];
    const float* K   = (const float*)d_in[2];
    const float* V   = (const float*)d_in[3];
    const float* Aoo = (const float*)d_in[4];
    const float* w   = (const float*)d_in[5];

    char* wsb = (char*)d_ws;                       // 16B-aligned offsets
    float*          Kt  = (float*)(wsb);                    // 1,179,648 B
    float*          qb_ = (float*)(wsb + 1179648);          //   196,608 B
    unsigned short* Qb  = (unsigned short*)(wsb + 1376256); //   589,824 B
    unsigned short* wab = (unsigned short*)(wsb + 1966080); //   294,912 B
    unsigned short* xb  = (unsigned short*)(wsb + 2260992); // 1,572,864 B
    unsigned short* W2  = (unsigned short*)(wsb + 3833856); // 9,437,184 B
    float* y = (float*)d_out;                      // total ws: ~13.3 MB

    k_prep<<<dim3(288), 256, 0, stream>>>(Q, K, Aoo, w, Kt, Qb, wab, y);
    k_gemm1x<<<dim3(1728), 256, 0, stream>>>(Qb, wab, Kt, x, V, W2, xb, qb_);
    k_gemm2y<<<dim3(288), 256, 0, stream>>>(W2, xb, qb_, y);
}

// Round 15
// 34.298 us; speedup vs baseline: 2.5482x; 1.1296x over previous
//
#include <hip/hip_runtime.h>

// Dims
#define SS 96       // spatial
#define CC 32       // latent
#define TT 16       // time
#define BP 16       // B*P
#define MM 3072     // CC*SS; m = c*96 + e == x's natural [c][e] flat layout
#define KTOT 49152  // TT*MM: flattened k2 = t*3072 + m for GEMM2
#define NKB 96      // split-K partials in GEMM2 (k-chunk 512)

typedef float f32x4 __attribute__((ext_vector_type(4)));
typedef short short8 __attribute__((ext_vector_type(8)));

// fp32 -> bf16 round-to-nearest-even
__device__ __forceinline__ unsigned short f2b(float f) {
    union { float f; unsigned u; } a; a.f = f;
    unsigned r = a.u + 0x7FFFu + ((a.u >> 16) & 1u);
    return (unsigned short)(r >> 16);
}

// Fragment-linear layouts (lane l consumes buf[tile][l][8] as one short8):
//  Qbf[(mtile*3+kt)*512 + l*8 + j]  : A of GEMM1. row m = mtile*16+(l&15),
//                                     k v = kt*32+(l>>4)*8+j
//  wabf[(X*3+kt)*512 + l*8 + j]    : B of GEMM1. col t = l&15, same v map
//  W2f[((xt*1536+tile)*64+l)*8+j]  : A of GEMM2. row X = xt*16+(l&15),
//                                     k2 = tile*32+(l>>4)*8+j
//  xbf[(tile*64+l)*8+j]            : B of GEMM2. col b = l&15, same k2 map

// ---------------------------------------------------------------------------
// K1: prep (grid 288):
//   [0,96):    Kt[X][m=c*96+e] = K[X][e*32+c]            (fp32, for epilogue)
//   [96,192):  Qbf from Q (one e-slab per block)
//   [192,288): wabf[X] = bf16(w[v]*Aoo[X][v*16+t])       (frag-linear)
__global__ __launch_bounds__(256) void k_prep(
    const float* __restrict__ Q, const float* __restrict__ K,
    const float* __restrict__ Aoo, const float* __restrict__ w,
    float* __restrict__ Kt, unsigned short* __restrict__ Qbf,
    unsigned short* __restrict__ wabf)
{
    __shared__ float sb[SS * 33];
    const int bid = blockIdx.x, tid = threadIdx.x;
    if (bid < 96) {
        const int X = bid;
        const float* src = K + (size_t)X * MM;
        float* dst = Kt + (size_t)X * MM;
        for (int i = tid; i < MM; i += 256) {
            int e = i >> 5, c = i & 31;
            sb[e * 33 + c] = src[i];
        }
        __syncthreads();
        for (int j = tid; j < MM; j += 256) {
            int c = j / SS, e = j - c * SS;
            dst[j] = sb[e * 33 + c];
        }
    } else if (bid < 192) {
        const int e = bid - 96;
        for (int i = tid; i < MM; i += 256) {          // i = v*32 + c
            int v = i >> 5, c = i & 31;
            sb[v * 33 + c] = Q[(size_t)v * MM + e * 32 + c];
        }
        __syncthreads();
        for (int g = tid; g < 384; g += 256) {         // g = c*12 + vg
            const int c = g / 12, vg = g - c * 12;
            const int mtile = c * 6 + (e >> 4);
            const int kt = vg >> 2;
            const int lane = ((vg & 3) << 4) | (e & 15);
            short8 o;
#pragma unroll
            for (int j = 0; j < 8; ++j)
                o[j] = (short)f2b(sb[(vg * 8 + j) * 33 + c]);
            *(short8*)(Qbf + (size_t)(mtile * 3 + kt) * 512 + lane * 8) = o;
        }
    } else {
        const int X = bid - 192;
        for (int i = tid; i < SS * TT; i += 256)       // i = v*16 + t
            sb[i] = Aoo[(size_t)X * (SS * TT) + i];
        if (tid < SS) sb[1600 + tid] = w[tid];
        __syncthreads();
        if (tid < 192) {                               // tid = kt*64 + l
            const int kt = tid >> 6, l = tid & 63;
            const int t = l & 15, v0 = kt * 32 + ((l >> 4) << 3);
            short8 o;
#pragma unroll
            for (int j = 0; j < 8; ++j)
                o[j] = (short)f2b(sb[1600 + v0 + j] * sb[(v0 + j) * 16 + t]);
            *(short8*)(wabf + (size_t)(X * 3 + kt) * 512 + l * 8) = o;
        }
    }
}

// ---------------------------------------------------------------------------
// K2 (grid 1440): GEMM1 + xbf convert + q GEMV.
//   [0,1152):    (X, mc): C[m(256) x t(16)] = Qbf x wabf^T; W2f = bf16(C*Kt).
//                All operand loads are lane-contiguous (1KB/instr).
//   [1152,1248): xbf convert: 512 k2 per block, LDS-staged, frag-linear out.
//   [1248,1440): q[bp][X][c] = sum_e V[X,e,c]*x[bp,T-1,c,e].
__global__ __launch_bounds__(256) void k_gemm1x(
    const unsigned short* __restrict__ Qbf, const unsigned short* __restrict__ wabf,
    const float* __restrict__ Kt, const float* __restrict__ x,
    const float* __restrict__ V, unsigned short* __restrict__ W2f,
    unsigned short* __restrict__ xbf, float* __restrict__ q)
{
    __shared__ __align__(16) union {
        unsigned short cvt[16][520];   // convert staging (+8 pad: bank spread)
        unsigned short w2s[4096];      // [16 t][256 m] epilogue restage
        float qsm[SS * 33];            // q-path x staging
    } sm;
    const int tid = threadIdx.x, bid = blockIdx.x;

    if (bid >= 1248) {
        // ---- q path: one block per (bp, xc)
        const int qb = bid - 1248;
        const int bp = qb / 12, xc = qb - (qb / 12) * 12;
        const float* xs = x + (size_t)bp * (TT * MM) + (TT - 1) * MM;  // [c][e]
        for (int i = tid; i < MM; i += 256) {
            int c = i / SS, e = i - (i / SS) * SS;
            sm.qsm[e * 33 + c] = xs[i];
        }
        __syncthreads();
        const int c = tid & 31, grp = tid >> 5;
        const int X = xc * 8 + grp;
        const float* Vp = V + (size_t)X * MM + c;
        float acc = 0.f;
#pragma unroll 8
        for (int e = 0; e < SS; ++e)
            acc = fmaf(Vp[e * CC], sm.qsm[e * 33 + c], acc);
        q[((size_t)bp * SS + X) * CC + c] = acc;
        return;
    }
    if (bid >= 1152) {
        // ---- xbf convert: k2 range [cb*512, +512) for all 16 b
        const int cb = bid - 1152;
        const int b = tid >> 4, cb32 = (tid & 15) * 32;
        const float* xp = x + (size_t)b * KTOT + cb * 512 + cb32;
#pragma unroll
        for (int k = 0; k < 32; k += 4) {
            float4 v4 = *(const float4*)(xp + k);
            sm.cvt[b][cb32 + k + 0] = f2b(v4.x);
            sm.cvt[b][cb32 + k + 1] = f2b(v4.y);
            sm.cvt[b][cb32 + k + 2] = f2b(v4.z);
            sm.cvt[b][cb32 + k + 3] = f2b(v4.w);
        }
        __syncthreads();
#pragma unroll
        for (int it = 0; it < 4; ++it) {
            const int i = tid + it * 256;          // i = kt2*64 + l
            const int kt2 = i >> 6, l = i & 63;
            short8 o = *(const short8*)(&sm.cvt[l & 15][kt2 * 32 + ((l >> 4) << 3)]);
            *(short8*)(xbf + ((size_t)(cb * 16 + kt2) * 64 + l) * 8) = o;
        }
        return;
    }
    // ---- GEMM1: (X, mc)
    const int X = bid / 12;
    const int mc = bid - X * 12;
    const int lane = tid & 63, wv = tid >> 6;
    const int l15 = lane & 15, lg = lane >> 4;

    const short8 bf0 = *(const short8*)(wabf + (size_t)(X * 3 + 0) * 512 + lane * 8);
    const short8 bf1 = *(const short8*)(wabf + (size_t)(X * 3 + 1) * 512 + lane * 8);
    const short8 bf2 = *(const short8*)(wabf + (size_t)(X * 3 + 2) * 512 + lane * 8);

    const f32x4 zero = {0.f, 0.f, 0.f, 0.f};
#pragma unroll
    for (int nt = 0; nt < 4; ++nt) {
        const int mtile = mc * 16 + wv * 4 + nt;
        const short8 a0 = *(const short8*)(Qbf + (size_t)(mtile * 3 + 0) * 512 + lane * 8);
        const short8 a1 = *(const short8*)(Qbf + (size_t)(mtile * 3 + 1) * 512 + lane * 8);
        const short8 a2 = *(const short8*)(Qbf + (size_t)(mtile * 3 + 2) * 512 + lane * 8);
        f32x4 acc = zero;
        acc = __builtin_amdgcn_mfma_f32_16x16x32_bf16(a0, bf0, acc, 0, 0, 0);
        acc = __builtin_amdgcn_mfma_f32_16x16x32_bf16(a1, bf1, acc, 0, 0, 0);
        acc = __builtin_amdgcn_mfma_f32_16x16x32_bf16(a2, bf2, acc, 0, 0, 0);
        const int mloc = wv * 64 + nt * 16 + lg * 4;   // local m (4 consecutive)
        const f32x4 kt4 = *(const f32x4*)(Kt + (size_t)X * MM + mc * 256 + mloc);
        ushort4 o;
        o.x = f2b(acc[0] * kt4[0]);
        o.y = f2b(acc[1] * kt4[1]);
        o.z = f2b(acc[2] * kt4[2]);
        o.w = f2b(acc[3] * kt4[3]);
        *(ushort4*)(sm.w2s + l15 * 256 + mloc) = o;    // C row t = l15
    }
    __syncthreads();
    // scatter into GEMM2-A fragment order: 16B granules (store-side only)
    const int xt = X >> 4, Xl = X & 15;
#pragma unroll
    for (int i = tid; i < 512; i += 256) {             // i = t*32 + mg
        const int t = i >> 5, mg = i & 31;
        short8 o = *(const short8*)(sm.w2s + t * 256 + mg * 8);
        const int tile = t * SS + mc * 8 + (mg >> 2);  // k2tile
        *(short8*)(W2f + ((size_t)(xt * 1536 + tile) * 64 + (mg & 3) * 16 + Xl) * 8) = o;
    }
}

// ---------------------------------------------------------------------------
// K3 (GEMM2 split-K, grid 576 = 96 kb x 6 xt): all loads lane-contiguous.
// Gp[(X*16+b)*96 + kb] plain store (no atomics). 4 waves x 4 MFMA.
__global__ __launch_bounds__(256) void k_gemm2(
    const unsigned short* __restrict__ W2f, const unsigned short* __restrict__ xbf,
    float* __restrict__ Gp)
{
    __shared__ float red[1024];
    const int tid = threadIdx.x, bid = blockIdx.x;
    const int kb = bid / 6, xt = bid - (bid / 6) * 6;
    const int lane = tid & 63, wv = tid >> 6;
    const int tbase = kb * 16 + wv * 4;

    f32x4 acc = {0.f, 0.f, 0.f, 0.f};
#pragma unroll
    for (int ks = 0; ks < 4; ++ks) {
        const int tile = tbase + ks;
        const short8 af = *(const short8*)(W2f + ((size_t)(xt * 1536 + tile) * 64 + lane) * 8);
        const short8 bf = *(const short8*)(xbf + ((size_t)tile * 64 + lane) * 8);
        acc = __builtin_amdgcn_mfma_f32_16x16x32_bf16(af, bf, acc, 0, 0, 0);
    }
#pragma unroll
    for (int r = 0; r < 4; ++r)
        red[(wv * 64 + lane) * 4 + r] = acc[r];
    __syncthreads();
    {   // C layout: col(l&15)=b, row((l>>4)*4+r)=Xl  (verified R11-R14)
        const int Xl = tid >> 4, b = tid & 15;
        const int l = ((Xl >> 2) << 4) | b, r = Xl & 3;
        float s = red[(0 * 64 + l) * 4 + r] + red[(1 * 64 + l) * 4 + r] +
                  red[(2 * 64 + l) * 4 + r] + red[(3 * 64 + l) * 4 + r];
        Gp[(size_t)((xt * 16 + Xl) * BP + b) * NKB + kb] = s;
    }
}

// ---------------------------------------------------------------------------
// K4: final (grid 16 = bp): G[X] = sum_kb Gp[(X*16+bp)*96+kb] (contiguous),
// y[bp,c] = sum_X q[bp,X,c]*G[X]. Plain stores; fully deterministic.
__global__ __launch_bounds__(256) void k_final(
    const float* __restrict__ Gp, const float* __restrict__ q,
    float* __restrict__ y)
{
    const int bp = blockIdx.x, tid = threadIdx.x;
    __shared__ float Gh[SS][2];
    __shared__ float G[SS];
    __shared__ float red2[8 * CC];
    if (tid < 192) {
        const int X = tid >> 1, h = tid & 1;
        const float* p = Gp + (size_t)(X * BP + bp) * NKB + h * 48;
        float s = 0.f;
#pragma unroll
        for (int j = 0; j < 12; ++j) {
            f32x4 v4 = *(const f32x4*)(p + j * 4);
            s += v4[0] + v4[1] + v4[2] + v4[3];
        }
        Gh[X][h] = s;
    }
    __syncthreads();
    if (tid < SS) G[tid] = Gh[tid][0] + Gh[tid][1];
    __syncthreads();

    const int c = tid & 31, grp = tid >> 5;
    float acc = 0.f;
#pragma unroll
    for (int k = 0; k < 12; ++k) {
        const int X = grp * 12 + k;
        acc = fmaf(q[((size_t)bp * SS + X) * CC + c], G[X], acc);
    }
    red2[grp * CC + c] = acc;
    __syncthreads();
    if (tid < CC) {
        float s = 0.f;
#pragma unroll
        for (int g8 = 0; g8 < 8; ++g8) s += red2[g8 * CC + tid];
        y[bp * CC + tid] = s;
    }
}

// ---------------------------------------------------------------------------
extern "C" void kernel_launch(void* const* d_in, const int* in_sizes, int n_in,
                              void* d_out, int out_size, void* d_ws, size_t ws_size,
                              hipStream_t stream) {
    const float* x   = (const float*)d_in[0];
    const float* Q   = (const float*)d_in[1];
    const float* K   = (const float*)d_in[2];
    const float* V   = (const float*)d_in[3];
    const float* Aoo = (const float*)d_in[4];
    const float* w   = (const float*)d_in[5];

    char* wsb = (char*)d_ws;                        // 16B-aligned offsets
    float*          Kt   = (float*)(wsb);                     // 1,179,648 B
    float*          Gp   = (float*)(wsb + 1179648);           //   589,824 B
    float*          qb_  = (float*)(wsb + 1769472);           //   196,608 B
    unsigned short* Qbf  = (unsigned short*)(wsb + 1966080);  //   589,824 B
    unsigned short* wabf = (unsigned short*)(wsb + 2555904);  //   294,912 B
    unsigned short* xbf  = (unsigned short*)(wsb + 2850816);  // 1,572,864 B
    unsigned short* W2f  = (unsigned short*)(wsb + 4423680);  // 9,437,184 B
    float* y = (float*)d_out;                       // total ws: ~13.9 MB

    k_prep<<<dim3(288), 256, 0, stream>>>(Q, K, Aoo, w, Kt, Qbf, wabf);
    k_gemm1x<<<dim3(1440), 256, 0, stream>>>(Qbf, wabf, Kt, x, V, W2f, xbf, qb_);
    k_gemm2<<<dim3(576), 256, 0, stream>>>(W2f, xbf, Gp);
    k_final<<<dim3(BP), 256, 0, stream>>>(Gp, qb_, y);
}

// Round 16
// 20.068 us; speedup vs baseline: 4.3552x; 1.7091x over previous
//
#include <hip/hip_runtime.h>

// Dims
#define SS 96       // spatial
#define CC 32       // latent
#define TT 16       // time
#define BP 16       // B*P
#define MM 3072     // CC*SS; m = c*96 + e == x's natural [c][e] flat layout
#define KTOT 49152  // TT*MM: flattened k2 = t*3072 + m for GEMM2
#define NKB 96      // split-K partials (one per mc chunk of 32 m)

typedef float f32x4 __attribute__((ext_vector_type(4)));
typedef short short8 __attribute__((ext_vector_type(8)));

// fp32 -> bf16 round-to-nearest-even
__device__ __forceinline__ unsigned short f2b(float f) {
    union { float f; unsigned u; } a; a.f = f;
    unsigned r = a.u + 0x7FFFu + ((a.u >> 16) & 1u);
    return (unsigned short)(r >> 16);
}

// Fragment-linear layouts (lane l consumes buf[tile][l][8] as one short8):
//  Qbf[(mtile*3+kt)*512 + l*8 + j] : A of GEMM1. row m = mtile*16+(l&15),
//                                    k v = kt*32+(l>>4)*8+j
//  wabf[(X*3+kt)*512 + l*8 + j]   : B of GEMM1. col t = l&15, same v map
//  xbf[(tile*64+l)*8 + j]         : B of GEMM2. col b = l&15,
//                                    k2 = tile*32+(l>>4)*8+j, tile = t*96+mc

// ---------------------------------------------------------------------------
// K1: prep-all (grid 576) — everything that depends only on inputs:
//   [0,96):    Kt[X][m=c*96+e] = K[X][e*32+c]            (fp32, epilogue)
//   [96,192):  Qbf from Q (one e-slab per block)
//   [192,288): wabf[X] = bf16(w[v]*Aoo[X][v*16+t])       (frag-linear)
//   [288,384): xbf = bf16(x), frag-linear
//   [384,576): q[bp][X][c] = sum_e V[X,e,c]*x[bp,T-1,c,e]
__global__ __launch_bounds__(256) void k_prep(
    const float* __restrict__ x, const float* __restrict__ Q,
    const float* __restrict__ K, const float* __restrict__ V,
    const float* __restrict__ Aoo, const float* __restrict__ w,
    float* __restrict__ Kt, unsigned short* __restrict__ Qbf,
    unsigned short* __restrict__ wabf, unsigned short* __restrict__ xbf,
    float* __restrict__ q)
{
    __shared__ __align__(16) union {
        float sb[SS * 33];
        unsigned short cvt[16][520];
    } sm;
    const int bid = blockIdx.x, tid = threadIdx.x;
    if (bid < 96) {
        const int X = bid;
        const float* src = K + (size_t)X * MM;
        float* dst = Kt + (size_t)X * MM;
        for (int i = tid; i < MM; i += 256) {
            int e = i >> 5, c = i & 31;
            sm.sb[e * 33 + c] = src[i];
        }
        __syncthreads();
        for (int j = tid; j < MM; j += 256) {
            int c = j / SS, e = j - c * SS;
            dst[j] = sm.sb[e * 33 + c];
        }
    } else if (bid < 192) {
        const int e = bid - 96;
        for (int i = tid; i < MM; i += 256) {          // i = v*32 + c
            int v = i >> 5, c = i & 31;
            sm.sb[v * 33 + c] = Q[(size_t)v * MM + e * 32 + c];
        }
        __syncthreads();
        for (int g = tid; g < 384; g += 256) {         // g = c*12 + vg
            const int c = g / 12, vg = g - c * 12;
            const int mtile = c * 6 + (e >> 4);
            const int kt = vg >> 2;
            const int lane = ((vg & 3) << 4) | (e & 15);
            short8 o;
#pragma unroll
            for (int j = 0; j < 8; ++j)
                o[j] = (short)f2b(sm.sb[(vg * 8 + j) * 33 + c]);
            *(short8*)(Qbf + (size_t)(mtile * 3 + kt) * 512 + lane * 8) = o;
        }
    } else if (bid < 288) {
        const int X = bid - 192;
        for (int i = tid; i < SS * TT; i += 256)       // i = v*16 + t
            sm.sb[i] = Aoo[(size_t)X * (SS * TT) + i];
        if (tid < SS) sm.sb[1600 + tid] = w[tid];
        __syncthreads();
        if (tid < 192) {                               // tid = kt*64 + l
            const int kt = tid >> 6, l = tid & 63;
            const int t = l & 15, v0 = kt * 32 + ((l >> 4) << 3);
            short8 o;
#pragma unroll
            for (int j = 0; j < 8; ++j)
                o[j] = (short)f2b(sm.sb[1600 + v0 + j] * sm.sb[(v0 + j) * 16 + t]);
            *(short8*)(wabf + (size_t)(X * 3 + kt) * 512 + l * 8) = o;
        }
    } else if (bid < 384) {
        // ---- xbf convert: k2 range [cb*512, +512) for all 16 b
        const int cb = bid - 288;
        const int b = tid >> 4, cb32 = (tid & 15) * 32;
        const float* xp = x + (size_t)b * KTOT + cb * 512 + cb32;
#pragma unroll
        for (int k = 0; k < 32; k += 4) {
            float4 v4 = *(const float4*)(xp + k);
            sm.cvt[b][cb32 + k + 0] = f2b(v4.x);
            sm.cvt[b][cb32 + k + 1] = f2b(v4.y);
            sm.cvt[b][cb32 + k + 2] = f2b(v4.z);
            sm.cvt[b][cb32 + k + 3] = f2b(v4.w);
        }
        __syncthreads();
#pragma unroll
        for (int it = 0; it < 4; ++it) {
            const int i = tid + it * 256;              // i = kt2*64 + l
            const int kt2 = i >> 6, l = i & 63;
            short8 o = *(const short8*)(&sm.cvt[l & 15][kt2 * 32 + ((l >> 4) << 3)]);
            *(short8*)(xbf + ((size_t)(cb * 16 + kt2) * 64 + l) * 8) = o;
        }
    } else {
        // ---- q path: one block per (bp, xc)
        const int qb = bid - 384;
        const int bp = qb / 12, xc = qb - (qb / 12) * 12;
        const float* xs = x + (size_t)bp * (TT * MM) + (TT - 1) * MM;  // [c][e]
        for (int i = tid; i < MM; i += 256) {
            int c = i / SS, e = i - (i / SS) * SS;
            sm.sb[e * 33 + c] = xs[i];
        }
        __syncthreads();
        const int c = tid & 31, grp = tid >> 5;
        const int X = xc * 8 + grp;
        const float* Vp = V + (size_t)X * MM + c;
        float acc = 0.f;
#pragma unroll 8
        for (int e = 0; e < SS; ++e)
            acc = fmaf(Vp[e * CC], sm.sb[e * 33 + c], acc);
        q[((size_t)bp * SS + X) * CC + c] = acc;
    }
}

// ---------------------------------------------------------------------------
// K2: fused GEMM1 -> LDS -> GEMM2 (grid 576 = 96 mc x 6 xt, XCD-chunked).
// Per block: W2 tile [16X x 16t x 32m] computed via GEMM1 MFMAs, scattered
// into LDS in GEMM2-A fragment order (tile=t, pad 4 ushorts -> the scatter's
// lane stride is 1032B = 2 banks: all 32 banks hit once, conflict-free),
// then 4 GEMM2 MFMAs per wave against global xbf frags. W2 never leaves LDS.
// Gp[(X*16+b)*96 + mc] plain store (split-K partials, fixed-order sum in K3).
__global__ __launch_bounds__(256) void k_fused(
    const unsigned short* __restrict__ Qbf, const unsigned short* __restrict__ wabf,
    const float* __restrict__ Kt, const unsigned short* __restrict__ xbf,
    float* __restrict__ Gp)
{
    __shared__ __align__(16) unsigned short w2s[16 * 516];  // 16 k2-tiles + pad
    __shared__ float red[1024];
    const int flat = blockIdx.x;
    const int bid = (flat & 7) * 72 + (flat >> 3);  // XCD chunk (576 = 8*72)
    const int mc = bid / 6, xt = bid - (bid / 6) * 6;
    const int tid = threadIdx.x;
    const int lane = tid & 63, wv = tid >> 6;
    const int l15 = lane & 15, lg = lane >> 4;

    // GEMM1 A-frags for mtiles {2mc, 2mc+1} — shared by all 16 X
    short8 af[2][3];
#pragma unroll
    for (int mtl = 0; mtl < 2; ++mtl)
#pragma unroll
        for (int kt = 0; kt < 3; ++kt)
            af[mtl][kt] = *(const short8*)(
                Qbf + (size_t)((mc * 2 + mtl) * 3 + kt) * 512 + lane * 8);

#pragma unroll
    for (int xi = 0; xi < 4; ++xi) {
        const int Xl = wv * 4 + xi;                 // wave owns 4 X rows
        const int X = xt * 16 + Xl;
        const unsigned short* bw = wabf + (size_t)X * 3 * 512 + lane * 8;
        const short8 b0 = *(const short8*)(bw);
        const short8 b1 = *(const short8*)(bw + 512);
        const short8 b2 = *(const short8*)(bw + 1024);
#pragma unroll
        for (int mtl = 0; mtl < 2; ++mtl) {
            f32x4 acc = {0.f, 0.f, 0.f, 0.f};
            acc = __builtin_amdgcn_mfma_f32_16x16x32_bf16(af[mtl][0], b0, acc, 0, 0, 0);
            acc = __builtin_amdgcn_mfma_f32_16x16x32_bf16(af[mtl][1], b1, acc, 0, 0, 0);
            acc = __builtin_amdgcn_mfma_f32_16x16x32_bf16(af[mtl][2], b2, acc, 0, 0, 0);
            // C: col(l15)=t, rows m_local = mtl*16 + lg*4 + r
            const int mloc = mtl * 16 + lg * 4;
            const f32x4 kt4 = *(const f32x4*)(Kt + (size_t)X * MM + mc * 32 + mloc);
            ushort4 o;
            o.x = f2b(acc[0] * kt4[0]);
            o.y = f2b(acc[1] * kt4[1]);
            o.z = f2b(acc[2] * kt4[2]);
            o.w = f2b(acc[3] * kt4[3]);
            // scatter to GEMM2-A frag order: tile t=l15, lane (k>>3)*16+Xl, elem k&7
            *(ushort4*)(&w2s[l15 * 516 + ((mloc >> 3) * 16 + Xl) * 8 + (lg & 1) * 4]) = o;
        }
    }
    __syncthreads();

    // GEMM2: wave wv handles t = wv*4..+4; A from LDS, B from global xbf
    f32x4 acc2 = {0.f, 0.f, 0.f, 0.f};
#pragma unroll
    for (int ts = 0; ts < 4; ++ts) {
        const int t = wv * 4 + ts;
        const short8 a2 = *(const short8*)(&w2s[t * 516 + lane * 8]);
        const short8 b2f = *(const short8*)(xbf + ((size_t)(t * SS + mc) * 64 + lane) * 8);
        acc2 = __builtin_amdgcn_mfma_f32_16x16x32_bf16(a2, b2f, acc2, 0, 0, 0);
    }
#pragma unroll
    for (int r = 0; r < 4; ++r)
        red[(wv * 64 + lane) * 4 + r] = acc2[r];
    __syncthreads();
    {   // C layout: col(l&15)=b, row((l>>4)*4+r)=Xl  (verified R11-R15)
        const int Xl = tid >> 4, b = tid & 15;
        const int l = ((Xl >> 2) << 4) | b, r = Xl & 3;
        float s = red[(0 * 64 + l) * 4 + r] + red[(1 * 64 + l) * 4 + r] +
                  red[(2 * 64 + l) * 4 + r] + red[(3 * 64 + l) * 4 + r];
        Gp[(size_t)((xt * 16 + Xl) * BP + b) * NKB + mc] = s;
    }
}

// ---------------------------------------------------------------------------
// K3: final (grid 16 = bp): G[X] = sum_mc Gp[(X*16+bp)*96+mc] (contiguous,
// fixed order), y[bp,c] = sum_X q[bp,X,c]*G[X]. Deterministic plain stores.
__global__ __launch_bounds__(256) void k_final(
    const float* __restrict__ Gp, const float* __restrict__ q,
    float* __restrict__ y)
{
    const int bp = blockIdx.x, tid = threadIdx.x;
    __shared__ float Gh[SS][2];
    __shared__ float G[SS];
    __shared__ float red2[8 * CC];
    if (tid < 192) {
        const int X = tid >> 1, h = tid & 1;
        const float* p = Gp + (size_t)(X * BP + bp) * NKB + h * 48;
        float s = 0.f;
#pragma unroll
        for (int j = 0; j < 12; ++j) {
            f32x4 v4 = *(const f32x4*)(p + j * 4);
            s += v4[0] + v4[1] + v4[2] + v4[3];
        }
        Gh[X][h] = s;
    }
    __syncthreads();
    if (tid < SS) G[tid] = Gh[tid][0] + Gh[tid][1];
    __syncthreads();

    const int c = tid & 31, grp = tid >> 5;
    float acc = 0.f;
#pragma unroll
    for (int k = 0; k < 12; ++k) {
        const int X = grp * 12 + k;
        acc = fmaf(q[((size_t)bp * SS + X) * CC + c], G[X], acc);
    }
    red2[grp * CC + c] = acc;
    __syncthreads();
    if (tid < CC) {
        float s = 0.f;
#pragma unroll
        for (int g8 = 0; g8 < 8; ++g8) s += red2[g8 * CC + tid];
        y[bp * CC + tid] = s;
    }
}

// ---------------------------------------------------------------------------
extern "C" void kernel_launch(void* const* d_in, const int* in_sizes, int n_in,
                              void* d_out, int out_size, void* d_ws, size_t ws_size,
                              hipStream_t stream) {
    const float* x   = (const float*)d_in[0];
    const float* Q   = (const float*)d_in[1];
    const float* K   = (const float*)d_in[2];
    const float* V   = (const float*)d_in[3];
    const float* Aoo = (const float*)d_in[4];
    const float* w   = (const float*)d_in[5];

    char* wsb = (char*)d_ws;                        // 16B-aligned offsets
    float*          Kt   = (float*)(wsb);                     // 1,179,648 B
    float*          Gp   = (float*)(wsb + 1179648);           //   589,824 B
    float*          qb_  = (float*)(wsb + 1769472);           //   196,608 B
    unsigned short* Qbf  = (unsigned short*)(wsb + 1966080);  //   589,824 B
    unsigned short* wabf = (unsigned short*)(wsb + 2555904);  //   294,912 B
    unsigned short* xbf  = (unsigned short*)(wsb + 2850816);  // 1,572,864 B
    float* y = (float*)d_out;                       // total ws: ~4.4 MB

    k_prep<<<dim3(576), 256, 0, stream>>>(x, Q, K, V, Aoo, w, Kt, Qbf, wabf,
                                          xbf, qb_);
    k_fused<<<dim3(576), 256, 0, stream>>>(Qbf, wabf, Kt, xbf, Gp);
    k_final<<<dim3(BP), 256, 0, stream>>>(Gp, qb_, y);
}